// Round 9
// baseline (241.828 us; speedup 1.0000x reference)
//
#include <hip/hip_runtime.h>
#include <stdint.h>

typedef unsigned short u16;
typedef unsigned int u32;
typedef __attribute__((ext_vector_type(8))) short short8;    // 8 bf16 (4 VGPRs)
typedef __attribute__((ext_vector_type(4))) float f32x4;
typedef __attribute__((ext_vector_type(16))) float f32x16;
typedef __attribute__((ext_vector_type(4))) unsigned short u16x4;

#define DEV static __device__ __forceinline__

DEV float bf2f(u16 b) { return __uint_as_float(((uint32_t)b) << 16); }
DEV u16 f2bf(float f) {
  uint32_t u = __float_as_uint(f);
  u += 0x7FFFu + ((u >> 16) & 1u);   // round-to-nearest-even
  return (u16)(u >> 16);
}
DEV void gld16(const u16* gsrc, u16* ldsdst) {
  __builtin_amdgcn_global_load_lds((const __attribute__((address_space(1))) void*)gsrc,
                                   (__attribute__((address_space(3))) void*)ldsdst, 16, 0, 0);
}
#define MFMA16(a, b, c) __builtin_amdgcn_mfma_f32_16x16x32_bf16(a, b, c, 0, 0, 0)
#define MFMA32(a, b, c) __builtin_amdgcn_mfma_f32_32x32x16_bf16(a, b, c, 0, 0, 0)

#define WAITVM4() asm volatile("s_waitcnt vmcnt(4)" ::: "memory")
#define WAITVM0() asm volatile("s_waitcnt vmcnt(0)" ::: "memory")
DEV void barrier() {
  asm volatile("" ::: "memory");
  __builtin_amdgcn_s_barrier();
  asm volatile("" ::: "memory");
}

#if __has_builtin(__builtin_amdgcn_exp2f)
DEV float fexp2(float x) { return __builtin_amdgcn_exp2f(x); }
#else
DEV float fexp2(float x) { return exp2f(x); }
#endif

DEV u32 cvtpk(float lo, float hi) {
  u32 r;
  asm("v_cvt_pk_bf16_f32 %0, %1, %2" : "=v"(r) : "v"(lo), "v"(hi));
  return r;
}

// ---------------------------------------------------------------------------
// fp32 -> bf16 conversion: x (8192x1024) + Wq,Wk,Wv,Wo (1024x1024 each)
// ---------------------------------------------------------------------------
__global__ __launch_bounds__(256) void k_convert(
    const float* __restrict__ x, const float* __restrict__ wq, const float* __restrict__ wk,
    const float* __restrict__ wv, const float* __restrict__ wo, u16* __restrict__ ws)
{
  int bid = blockIdx.x, t = threadIdx.x;
  const float* src; u16* dst; size_t off;
  if (bid < 8192) { src = x; dst = ws; off = (size_t)bid * 1024; }
  else {
    int r = bid - 8192; int sel = r >> 10; int lb = r & 1023;
    src = sel == 0 ? wq : sel == 1 ? wk : sel == 2 ? wv : wo;
    dst = ws + 8388608u + (size_t)sel * 1048576u;
    off = (size_t)lb * 1024;
  }
  size_t e = off + (size_t)t * 4;
  f32x4 v = *(const f32x4*)(src + e);
  u16x4 o;
  o.x = f2bf(v.x); o.y = f2bf(v.y); o.z = f2bf(v.z); o.w = f2bf(v.w);
  *(u16x4*)(dst + e) = o;
}

// ---------------------------------------------------------------------------
// Shared GEMM main loop — R3/R8-proven single-buffered form (16KB LDS)
// ---------------------------------------------------------------------------
DEV void gemm_mainloop(const u16* __restrict__ A, const u16* __restrict__ B,
                       int m0, int n0, u16* As, u16* Bs, f32x4 acc[4][4])
{
  const int tid = threadIdx.x, lane = tid & 63, w = tid >> 6;
  const int fr = lane & 15, g = lane >> 4;
  const int wm = w >> 1, wn = w & 1;

  const int rowA0 = (w * 2 + 0) * 16 + (lane >> 2);
  const int rowA1 = (w * 2 + 1) * 16 + (lane >> 2);
  const int ci = lane & 3;
  const u16* ga0 = A + (size_t)(m0 + rowA0) * 1024 + ((ci ^ (rowA0 & 3)) << 3);
  const u16* ga1 = A + (size_t)(m0 + rowA1) * 1024 + ((ci ^ (rowA1 & 3)) << 3);
  const u16* gb0 = B + (size_t)(n0 + rowA0) * 1024 + ((ci ^ (rowA0 & 3)) << 3);
  const u16* gb1 = B + (size_t)(n0 + rowA1) * 1024 + ((ci ^ (rowA1 & 3)) << 3);
  u16* lA0 = As + (w * 2 + 0) * 512;
  u16* lA1 = As + (w * 2 + 1) * 512;
  u16* lB0 = Bs + (w * 2 + 0) * 512;
  u16* lB1 = Bs + (w * 2 + 1) * 512;

  int raf[4], rbf[4];
#pragma unroll
  for (int i = 0; i < 4; ++i) {
    int rA = wm * 64 + i * 16 + fr;
    raf[i] = rA * 32 + ((g ^ (rA & 3)) << 3);
    int rB = wn * 64 + i * 16 + fr;
    rbf[i] = rB * 32 + ((g ^ (rB & 3)) << 3);
  }

  for (int k0 = 0; k0 < 1024; k0 += 32) {
    __syncthreads();
    gld16(ga0 + k0, lA0);
    gld16(ga1 + k0, lA1);
    gld16(gb0 + k0, lB0);
    gld16(gb1 + k0, lB1);
    __syncthreads();
    short8 af[4], bf[4];
#pragma unroll
    for (int i = 0; i < 4; ++i) af[i] = *(const short8*)&As[raf[i]];
#pragma unroll
    for (int i = 0; i < 4; ++i) bf[i] = *(const short8*)&Bs[rbf[i]];
#pragma unroll
    for (int mi = 0; mi < 4; ++mi)
#pragma unroll
      for (int ni = 0; ni < 4; ++ni)
        acc[mi][ni] = MFMA16(af[mi], bf[ni], acc[mi][ni]);
  }
}

// ---------------------------------------------------------------------------
// QKV projection. Q written *0.125*log2(e) (folds attention scale + exp2 domain)
// ---------------------------------------------------------------------------
__global__ __launch_bounds__(256) void k_gemm_qkv(
    const u16* __restrict__ xb, const u16* __restrict__ wqb, const u16* __restrict__ wkb,
    const u16* __restrict__ wvb, const float* __restrict__ bq, const float* __restrict__ bk,
    const float* __restrict__ bv, u16* __restrict__ Qg, u16* __restrict__ Kg,
    u16* __restrict__ Vtg)
{
  __shared__ u16 As[128 * 32], Bs[128 * 32];
  const int mb = blockIdx.x, nb_all = blockIdx.y;
  const int mat = nb_all >> 3, nb = nb_all & 7;
  const u16* W = mat == 0 ? wqb : (mat == 1 ? wkb : wvb);
  const float* bias = mat == 0 ? bq : (mat == 1 ? bk : bv);
  const int m0 = mb * 128, n0 = nb * 128;

  f32x4 acc[4][4];
  f32x4 z = {0.f, 0.f, 0.f, 0.f};
#pragma unroll
  for (int i = 0; i < 4; ++i)
#pragma unroll
    for (int j = 0; j < 4; ++j) acc[i][j] = z;

  gemm_mainloop(xb, W, m0, n0, As, Bs, acc);

  const int tid = threadIdx.x, lane = tid & 63, w = tid >> 6;
  const int fr = lane & 15, g = lane >> 4;
  const int wm = w >> 1, wn = w & 1;

  if (mat <= 1) {
    u16* Og = mat == 0 ? Qg : Kg;
    const float scale = mat == 0 ? 0.18033688011112042f : 1.0f;
#pragma unroll
    for (int mi = 0; mi < 4; ++mi)
#pragma unroll
      for (int ni = 0; ni < 4; ++ni) {
        int n = n0 + wn * 64 + ni * 16 + fr;
        float bv_ = bias[n];
        int h = n >> 6, d = n & 63;
#pragma unroll
        for (int r = 0; r < 4; ++r) {
          int m = m0 + wm * 64 + mi * 16 + 4 * g + r;
          int b = m >> 11, s = m & 2047;
          float v = (acc[mi][ni][r] + bv_) * scale;
          Og[(((size_t)(b * 16 + h)) * 2048 + (size_t)s) * 64 + d] = f2bf(v);
        }
      }
  } else {
#pragma unroll
    for (int mi = 0; mi < 4; ++mi)
#pragma unroll
      for (int ni = 0; ni < 4; ++ni) {
        int n = n0 + wn * 64 + ni * 16 + fr;
        float bv_ = bias[n];
        int h = n >> 6, d = n & 63;
        int mbase = m0 + wm * 64 + mi * 16 + 4 * g;
        int b = mbase >> 11, s0 = mbase & 2047;
        u16x4 pk;
        pk.x = f2bf(acc[mi][ni][0] + bv_);
        pk.y = f2bf(acc[mi][ni][1] + bv_);
        pk.z = f2bf(acc[mi][ni][2] + bv_);
        pk.w = f2bf(acc[mi][ni][3] + bv_);
        *(u16x4*)&Vtg[(((size_t)(b * 16 + h)) * 64 + d) * 2048 + s0] = pk;
      }
  }
}

// ---------------------------------------------------------------------------
// Flash attention, 32x32x16-MFMA form. grid 1024 (16 qb x 64 bh via XCD swz),
// 4 waves x 32 q-rows, KVBLK=64, double-buffered K/V (32KB LDS), counted-vmcnt
// prefetch (verified protocol).
//  QK^T: S^T-tile = mfma32(K-frag, Q-frag); C: col=q=lane&31 (softmax lane-local),
//        row=k=(reg&3)+8(reg>>2)+4(lane>>5).
//  PV (swapped): O^T = mfma32(V-frag, P^T-frag); C: col=q lane-local -> alpha
//        and 1/l rescale need no shuffles; epilogue u16x4 stores.
//  P^T B-frag: lane needs k=16s+8*h5+e; own regs hold half, partner (lane^32)
//        holds the other -> 2 shfl_xor(32) + cndmask selects per slice.
// ---------------------------------------------------------------------------
__global__ __launch_bounds__(256) void k_attn(
    const u16* __restrict__ Qg, const u16* __restrict__ Kg, const u16* __restrict__ Vtg,
    u16* __restrict__ headb)
{
  __shared__ u16 K_lds[2][64 * 64];  // 2 x 8KB
  __shared__ u16 V_lds[2][64 * 64];  // 2 x 8KB
  const int tid = threadIdx.x, lane = tid & 63, w = tid >> 6;
  const int l31 = lane & 31, h5 = lane >> 5, k7 = lane & 7;
  const bool lo_half = (h5 == 0);
  // XCD swizzle (bijective: 1024 % 8 == 0)
  const int swz = ((blockIdx.x & 7) << 7) + (blockIdx.x >> 3);
  const int qb = swz & 15, bh = swz >> 4;
  const u16* Qbase = Qg + (size_t)bh * 2048 * 64;
  const u16* Kbase = Kg + (size_t)bh * 2048 * 64;
  const u16* Vbase = Vtg + (size_t)bh * 64 * 2048;

  // staging: per tile 8 chunks of 1KB (K rows 64x128B; V^T rows 64x128B window)
  const int ck0 = w * 2, ck1 = w * 2 + 1;
  const int srow0 = ck0 * 8 + (lane >> 3), srow1 = ck1 * 8 + (lane >> 3);
  const int sci = lane & 7;
  const u16* gk0 = Kbase + (size_t)srow0 * 64 + ((sci ^ (srow0 & 7)) << 3);
  const u16* gk1 = Kbase + (size_t)srow1 * 64 + ((sci ^ (srow1 & 7)) << 3);
  const u16* gv0 = Vbase + (size_t)srow0 * 2048 + ((sci ^ (srow0 & 7)) << 3);
  const u16* gv1 = Vbase + (size_t)srow1 * 2048 + ((sci ^ (srow1 & 7)) << 3);

  // Q fragments (B-operand): Q[q=l31][d=16j+8*h5+e], pre-scaled by 0.125*log2e
  short8 qf[4];
  {
    const u16* qrow = Qbase + (size_t)(qb * 128 + w * 32 + l31) * 64;
#pragma unroll
    for (int j = 0; j < 4; ++j)
      qf[j] = *(const short8*)&qrow[j * 16 + h5 * 8];
  }

  // swizzled chunk offsets for compute reads (c = 2j + h5, XOR row&7 = lane&7)
  int cj[4];
#pragma unroll
  for (int j = 0; j < 4; ++j) cj[j] = (((2 * j + h5) ^ k7) << 3);
  const int rb = l31 * 64;   // row-base within LDS tile (row = {kb,dh}*32 + l31)

  f32x16 po0, po1;
#pragma unroll
  for (int e = 0; e < 16; ++e) { po0[e] = 0.f; po1[e] = 0.f; }
  float mrun = -1e30f, lrun = 0.f;

  // prologue: stage tile 0 into buf 0
  gld16(gk0, K_lds[0] + ck0 * 512);
  gld16(gk1, K_lds[0] + ck1 * 512);
  gld16(gv0, V_lds[0] + ck0 * 512);
  gld16(gv1, V_lds[0] + ck1 * 512);

  for (int kv = 0; kv < 32; ++kv) {
    const int cur = kv & 1;
    if (kv < 31) {
      const int ko = (kv + 1) * 64 * 64;   // K: 64 rows x 64
      const int vo = (kv + 1) * 64;        // V^T: 64 cols
      gld16(gk0 + ko, K_lds[cur ^ 1] + ck0 * 512);
      gld16(gk1 + ko, K_lds[cur ^ 1] + ck1 * 512);
      gld16(gv0 + vo, V_lds[cur ^ 1] + ck0 * 512);
      gld16(gv1 + vo, V_lds[cur ^ 1] + ck1 * 512);
      WAITVM4();
    } else {
      WAITVM0();
    }
    barrier();
    const u16* Kc = K_lds[cur];
    const u16* Vc = V_lds[cur];

    // S^T = K Q^T : s0 = k-rows 0..31, s1 = k-rows 32..63; col q = l31
    f32x16 s0, s1;
#pragma unroll
    for (int e = 0; e < 16; ++e) { s0[e] = 0.f; s1[e] = 0.f; }
    __builtin_amdgcn_s_setprio(1);
#pragma unroll
    for (int j = 0; j < 4; ++j) {
      short8 kf0 = *(const short8*)&Kc[rb + cj[j]];
      short8 kf1 = *(const short8*)&Kc[2048 + rb + cj[j]];
      s0 = MFMA32(kf0, qf[j], s0);
      s1 = MFMA32(kf1, qf[j], s1);
    }
    __builtin_amdgcn_s_setprio(0);

    // online softmax (q = l31 lane-local; partner lane^32 holds other k-halves)
    float mx = fmaxf(s0[0], s1[0]);
#pragma unroll
    for (int e = 1; e < 16; ++e) mx = fmaxf(mx, fmaxf(s0[e], s1[e]));
    mx = fmaxf(mx, __shfl_xor(mx, 32, 64));
    const bool defer = __all(mx - mrun <= 8.0f);
    const float mnew = defer ? mrun : mx;
#pragma unroll
    for (int e = 0; e < 16; ++e) {
      s0[e] = fexp2(s0[e] - mnew);
      s1[e] = fexp2(s1[e] - mnew);
    }
    float a0 = 0.f, a1 = 0.f, a2 = 0.f, a3 = 0.f;
#pragma unroll
    for (int e = 0; e < 4; ++e) {
      a0 += s0[4 * e + 0] + s1[4 * e + 0];
      a1 += s0[4 * e + 1] + s1[4 * e + 1];
      a2 += s0[4 * e + 2] + s1[4 * e + 2];
      a3 += s0[4 * e + 3] + s1[4 * e + 3];
    }
    float rs = (a0 + a1) + (a2 + a3);
    rs += __shfl_xor(rs, 32, 64);
    if (defer) {
      lrun += rs;
    } else {
      float alpha = fexp2(mrun - mnew);
      lrun = lrun * alpha + rs;
      mrun = mnew;
#pragma unroll
      for (int e = 0; e < 16; ++e) { po0[e] *= alpha; po1[e] *= alpha; }
    }

    // PV: per k-slice s (16 k's): build P^T B-frag in-register, 2 MFMA (d-halves)
    __builtin_amdgcn_s_setprio(1);
#pragma unroll
    for (int s = 0; s < 4; ++s) {
      // slice s regs: R[base..base+7] of (s<2 ? s0 : s1), base=(s&1)*8
      // k_local = (r&3) + 8*(r>=4) + 4*h5
      u32 lo0, lo1, hi0, hi1;
      if (s == 0)      { lo0 = cvtpk(s0[0], s0[1]);  lo1 = cvtpk(s0[2], s0[3]);
                         hi0 = cvtpk(s0[4], s0[5]);  hi1 = cvtpk(s0[6], s0[7]); }
      else if (s == 1) { lo0 = cvtpk(s0[8], s0[9]);  lo1 = cvtpk(s0[10], s0[11]);
                         hi0 = cvtpk(s0[12], s0[13]); hi1 = cvtpk(s0[14], s0[15]); }
      else if (s == 2) { lo0 = cvtpk(s1[0], s1[1]);  lo1 = cvtpk(s1[2], s1[3]);
                         hi0 = cvtpk(s1[4], s1[5]);  hi1 = cvtpk(s1[6], s1[7]); }
      else             { lo0 = cvtpk(s1[8], s1[9]);  lo1 = cvtpk(s1[10], s1[11]);
                         hi0 = cvtpk(s1[12], s1[13]); hi1 = cvtpk(s1[14], s1[15]); }
      // lane needs kk=8*h5+e: lo half misses k4-7 (partner's lo), hi half misses
      // k8-11 (partner's hi) -> exchange the opposite pair across lane^32
      u32 sent0 = lo_half ? hi0 : lo0;
      u32 sent1 = lo_half ? hi1 : lo1;
      u32 r0 = __shfl_xor(sent0, 32, 64);
      u32 r1 = __shfl_xor(sent1, 32, 64);
      union { u32 u[4]; short8 v; } pf;
      pf.u[0] = lo_half ? lo0 : r0;
      pf.u[1] = lo_half ? lo1 : r1;
      pf.u[2] = lo_half ? r0 : hi0;
      pf.u[3] = lo_half ? r1 : hi1;
      short8 vf0 = *(const short8*)&Vc[rb + cj[s]];
      short8 vf1 = *(const short8*)&Vc[2048 + rb + cj[s]];
      po0 = MFMA32(vf0, pf.v, po0);
      po1 = MFMA32(vf1, pf.v, po1);
    }
    __builtin_amdgcn_s_setprio(0);
    barrier();
  }

  // epilogue: O^T: lane owns q=l31; d = dh*32 + (reg&3)+8*(reg>>2)+4*h5
  const float linv = 1.0f / lrun;
  const int b = bh >> 4, h = bh & 15;
  const int srow = qb * 128 + w * 32 + l31;
  u16* rowp = headb + (size_t)(b * 2048 + srow) * 1024 + h * 64;
#pragma unroll
  for (int i = 0; i < 4; ++i) {
    u16x4 pk;
    pk.x = f2bf(po0[4 * i + 0] * linv);
    pk.y = f2bf(po0[4 * i + 1] * linv);
    pk.z = f2bf(po0[4 * i + 2] * linv);
    pk.w = f2bf(po0[4 * i + 3] * linv);
    *(u16x4*)&rowp[8 * i + 4 * h5] = pk;
    u16x4 pk2;
    pk2.x = f2bf(po1[4 * i + 0] * linv);
    pk2.y = f2bf(po1[4 * i + 1] * linv);
    pk2.z = f2bf(po1[4 * i + 2] * linv);
    pk2.w = f2bf(po1[4 * i + 3] * linv);
    *(u16x4*)&rowp[32 + 8 * i + 4 * h5] = pk2;
  }
}

// ---------------------------------------------------------------------------
// Output projection: proj = head @ Wo^T + bo  (bf16 out)
// ---------------------------------------------------------------------------
__global__ __launch_bounds__(256) void k_gemm_o(
    const u16* __restrict__ headb, const u16* __restrict__ wob, const float* __restrict__ bo,
    u16* __restrict__ projb)
{
  __shared__ u16 As[128 * 32], Bs[128 * 32];
  const int m0 = blockIdx.x * 128, n0 = blockIdx.y * 128;
  f32x4 acc[4][4];
  f32x4 z = {0.f, 0.f, 0.f, 0.f};
#pragma unroll
  for (int i = 0; i < 4; ++i)
#pragma unroll
    for (int j = 0; j < 4; ++j) acc[i][j] = z;

  gemm_mainloop(headb, wob, m0, n0, As, Bs, acc);

  const int tid = threadIdx.x, lane = tid & 63, w = tid >> 6;
  const int fr = lane & 15, g = lane >> 4;
  const int wm = w >> 1, wn = w & 1;
#pragma unroll
  for (int mi = 0; mi < 4; ++mi)
#pragma unroll
    for (int ni = 0; ni < 4; ++ni) {
      int n = n0 + wn * 64 + ni * 16 + fr;
      float bv_ = bo[n];
#pragma unroll
      for (int r = 0; r < 4; ++r) {
        int m = m0 + wm * 64 + mi * 16 + 4 * g + r;
        projb[(size_t)m * 1024 + n] = f2bf(acc[mi][ni][r] + bv_);
      }
    }
}

// ---------------------------------------------------------------------------
// LayerNorm + residual
// ---------------------------------------------------------------------------
__global__ __launch_bounds__(256) void k_ln(
    const u16* __restrict__ projb, const float* __restrict__ x,
    const float* __restrict__ gamma, const float* __restrict__ beta, float* __restrict__ out)
{
  __shared__ float sh1[4], sh2[4];
  const int row = blockIdx.x, t = threadIdx.x, lane = t & 63, w = t >> 6;
  const size_t base = (size_t)row * 1024;
  u16x4 pv = *(const u16x4*)&projb[base + t * 4];
  float v0 = bf2f(pv.x), v1 = bf2f(pv.y), v2 = bf2f(pv.z), v3 = bf2f(pv.w);
  float s1 = v0 + v1 + v2 + v3;
  float s2 = v0 * v0 + v1 * v1 + v2 * v2 + v3 * v3;
  for (int m = 1; m < 64; m <<= 1) {
    s1 += __shfl_xor(s1, m, 64);
    s2 += __shfl_xor(s2, m, 64);
  }
  if (lane == 0) { sh1[w] = s1; sh2[w] = s2; }
  __syncthreads();
  s1 = sh1[0] + sh1[1] + sh1[2] + sh1[3];
  s2 = sh2[0] + sh2[1] + sh2[2] + sh2[3];
  float mu = s1 * (1.0f / 1024.0f);
  float var = s2 * (1.0f / 1024.0f) - mu * mu;
  float rsd = rsqrtf(var + 1e-5f);
  f32x4 xv = *(const f32x4*)&x[base + t * 4];
  f32x4 res;
  int e = t * 4;
  res.x = xv.x + (v0 - mu) * rsd * gamma[e + 0] + beta[e + 0];
  res.y = xv.y + (v1 - mu) * rsd * gamma[e + 1] + beta[e + 1];
  res.z = xv.z + (v2 - mu) * rsd * gamma[e + 2] + beta[e + 2];
  res.w = xv.w + (v3 - mu) * rsd * gamma[e + 3] + beta[e + 3];
  *(f32x4*)&out[base + t * 4] = res;
}

// ---------------------------------------------------------------------------
extern "C" void kernel_launch(void* const* d_in, const int* in_sizes, int n_in,
                              void* d_out, int out_size, void* d_ws, size_t ws_size,
                              hipStream_t stream)
{
  const float* x     = (const float*)d_in[0];
  const float* Wq    = (const float*)d_in[1];
  const float* bq    = (const float*)d_in[2];
  const float* Wk    = (const float*)d_in[3];
  const float* bk    = (const float*)d_in[4];
  const float* Wv    = (const float*)d_in[5];
  const float* bv    = (const float*)d_in[6];
  const float* Wo    = (const float*)d_in[7];
  const float* bo    = (const float*)d_in[8];
  const float* gamma = (const float*)d_in[9];
  const float* beta  = (const float*)d_in[10];
  float* out = (float*)d_out;

  u16* ws   = (u16*)d_ws;
  u16* xb   = ws;                    // 8192*1024
  u16* wqb  = ws + 8388608;
  u16* wkb  = wqb + 1048576;
  u16* wvb  = wkb + 1048576;
  u16* wob  = wvb + 1048576;
  u16* Qg   = wob + 1048576;         // [64][2048][64]
  u16* Kg   = Qg + 8388608;          // [64][2048][64]
  u16* Vtg  = Kg + 8388608;          // [64][64][2048]
  u16* headb = Vtg + 8388608;        // [8192][1024]
  u16* projb = Qg;                   // reuse Q region (dead after attention)

  k_convert<<<12288, 256, 0, stream>>>(x, Wq, Wk, Wv, Wo, ws);
  k_gemm_qkv<<<dim3(64, 24), 256, 0, stream>>>(xb, wqb, wkb, wvb, bq, bk, bv, Qg, Kg, Vtg);
  k_attn<<<dim3(1024), 256, 0, stream>>>(Qg, Kg, Vtg, headb);
  k_gemm_o<<<dim3(64, 8), 256, 0, stream>>>(headb, wob, bo, projb);
  k_ln<<<8192, 256, 0, stream>>>(projb, x, gamma, beta, out);
}